// Round 11
// baseline (467.994 us; speedup 1.0000x reference)
//
#include <hip/hip_runtime.h>
#include <hip/hip_bf16.h>
#include <math.h>

// ---------------------------------------------------------------------------
// VQ quantizer:
//   in[0] = z        (16,256,32,32) fp32   -> N=16384 vectors of C=256
//   in[1] = codebook (8192,256)     fp32
//   out   = [ z_q (B,C,H,W) 4194304 | loss | ortho | perplexity | idx(16384) as float ]
//
// idx strategy (two-stage, bit-matching the R2..R10 passing semantics):
//   Stage A: bf16 MFMA GEMM; tilemin[t][n] = -2*max_j dot_approx (err<=1.54e-4)
//   Stage B: rows whose tilemin is within MARGIN of rowmin get the EXACT fp32
//            chain recomputed tile-centrically; d = fmaf(-2,acc, A_n + ce_j)
//            == R2 bits; packed-key atomicMin, lowest-index tie-break.
//
// R11 = R10 with (a) k_mfma A-side in registers (LDS holds only B; same MFMA
// accumulation order -> tilemin bits unchanged), (b) fp32 zT restored and
// refine2 z-staging reverted to the R5-verbatim coalesced form, (c) A[n]
// computed inside k_ztrans from the LDS tile (R2-verbatim chain -> same bits).
// ---------------------------------------------------------------------------

#define N_E     8192
#define C_DIM   256
#define N_VEC   16384            // 16*32*32
#define N_ELEM  4194304          // 16*256*32*32
#define MARGIN  6.0e-4f

// ws layout (bytes) -- zero-init fields packed first (single memset)
#define WS_COUNTS   0            // int[8192]                 32768
#define WS_M        32768        // float[65536]              262144
#define WS_ACCUM    294912       // double[2]                 16
#define WS_LISTLEN  294928       // int[64]                   256
#define WS_ZERO_BYTES 295184
#define WS_CE       295184       // float[8192]               32768
#define WS_RN       327952       // float[8192]               32768
#define WS_A        360720       // float[16384]              65536
#define WS_KEYS     426256       // u64[16384]                131072
#define WS_LISTS    557328       // int[64*16384]             4194304
#define WS_TILEMIN  4751632      // float[64*16384] [t][n]    4194304
#define WS_ZBF      8945936      // ushort[16384*256]         8388608
#define WS_CBBF     17334544     // ushort[8192*256]          4194304
#define WS_THR      21528848     // float[16384]              65536
#define WS_ZT       21594384     // float[16384*256]          16777216

typedef short short8v __attribute__((ext_vector_type(8)));
typedef float f32x4  __attribute__((ext_vector_type(4)));

__device__ inline unsigned short f2bf(float f) {       // RNE fp32->bf16 (no NaN in data)
    unsigned int x = __float_as_uint(f);
    return (unsigned short)((x + 0x7fffu + ((x >> 16) & 1u)) >> 16);
}

// ---------------------------------------------------------------------------
// codebook prep: row sqnorm ce (bits == R2..R10), recip norm rn, bf16 cast
__global__ __launch_bounds__(256) void k_cbprep(const float* __restrict__ cb,
                                                float* __restrict__ ce,
                                                float* __restrict__ rn,
                                                unsigned short* __restrict__ cbbf) {
    int j = blockIdx.x;
    int tid = threadIdx.x;
    float v = cb[(size_t)j * C_DIM + tid];
    cbbf[(size_t)j * C_DIM + tid] = f2bf(v);
    float s = v * v;
    #pragma unroll
    for (int off = 32; off > 0; off >>= 1) s += __shfl_down(s, off, 64);
    __shared__ float sh[4];
    if ((tid & 63) == 0) sh[tid >> 6] = s;
    __syncthreads();
    if (tid == 0) {
        float t = sh[0] + sh[1] + sh[2] + sh[3];
        ce[j] = t;
        rn[j] = 1.0f / sqrtf(t);
    }
}

// ---------------------------------------------------------------------------
// z prep: LDS-staged transpose -> zbf (bf16) + zT (fp32), both with coalesced
// 16B/lane writes; A[n] computed from the LDS tile with the R2-VERBATIM
// k-ascending fmaf chain (same values, same order -> identical bits).
__global__ __launch_bounds__(256) void k_ztrans(const float* __restrict__ z,
                                                unsigned short* __restrict__ zbf,
                                                float* __restrict__ zT,
                                                float* __restrict__ A) {
    __shared__ float tile[64 * 260];             // [hw][c], stride 260
    const int tid = threadIdx.x;
    const int n0 = blockIdx.x * 64;
    const int b = n0 >> 10, hw0 = n0 & 1023;
    const float* zp = z + (size_t)b * 262144 + hw0;

    const int hw = tid & 63, cg = tid >> 6;      // 4 c per pass, coalesced over hw
    #pragma unroll 8
    for (int p = 0; p < 64; ++p) {
        int c = p * 4 + cg;
        tile[hw * 260 + c] = zp[(size_t)c * 1024 + hw];
    }
    __syncthreads();

    if (tid < 64) {                              // A[n]: R2-verbatim chain
        float a = 0.0f;
        #pragma unroll 8
        for (int c = 0; c < C_DIM; ++c) {
            float v = tile[tid * 260 + c];
            a = fmaf(v, v, a);
        }
        A[n0 + tid] = a;
    }

    const int r = tid >> 2, q = tid & 3;         // row, 64-c quarter
    unsigned short* dst = zbf + (size_t)(n0 + r) * C_DIM + q * 64;
    float* dstT         = zT  + (size_t)(n0 + r) * C_DIM + q * 64;
    const float* src = &tile[r * 260 + q * 64];
    #pragma unroll
    for (int i = 0; i < 8; ++i) {
        f32x4 lo = *(const f32x4*)&src[i * 8];
        f32x4 hi = *(const f32x4*)&src[i * 8 + 4];
        *(f32x4*)&dstT[i * 8]     = lo;
        *(f32x4*)&dstT[i * 8 + 4] = hi;
        short8v u;
        #pragma unroll
        for (int x = 0; x < 4; ++x) { u[x] = (short)f2bf(lo[x]); u[4 + x] = (short)f2bf(hi[x]); }
        *(short8v*)(dst + i * 8) = u;            // 16B/lane, rows contiguous
    }
}

// ---------------------------------------------------------------------------
// Stage A: bf16 MFMA GEMM, 128n x 128j per block (4 waves, 2x2), K=256,
// 2-level XCD swizzle.  A-side fragments load GLOBAL->REGISTER directly in
// MFMA layout (16 rows x 64B aligned sectors, L2-hot panel); LDS holds only
// Bs -> LDS wave-ops per chunk halve (96 -> 48).  kc/kk/acc order identical
// to R7/R10 -> tilemin bits unchanged.
__global__ __launch_bounds__(256) void k_mfma(const unsigned short* __restrict__ zbf,
                                              const unsigned short* __restrict__ cbbf,
                                              float* __restrict__ tilemin) {
    __shared__ unsigned short Bs[128 * 72];   // [j][k]
    __shared__ float smin[128][2];

    const int tid = threadIdx.x;
    const int lin = blockIdx.x;
    const int x = lin & 7, r = lin >> 3;                  // XCD, rank within
    const int jp = r >> 7, q = r & 127;
    const int by = x * 16 + (q >> 3), bx = jp * 8 + (q & 7);
    const int n0 = by * 128, j0 = bx * 128;
    const int wave = tid >> 6, lane = tid & 63;
    const int wx = wave & 1, wy = wave >> 1;              // wave tile: 64n x 64j
    const int g = lane >> 4, c = lane & 15;
    const int kg = tid & 7, nl = tid >> 3;                // B staging decomposition

    // per-lane global base for A fragments: row = n0 + wy*64 + nf*16 + c
    const unsigned short* gA = zbf + (size_t)(n0 + wy * 64 + c) * C_DIM + g * 8;

    short8v rb[4];
    #pragma unroll
    for (int p = 0; p < 4; ++p)
        rb[p] = *(const short8v*)&cbbf[(size_t)(j0 + nl + 32 * p) * C_DIM + kg * 8];

    f32x4 acc[4][4];
    #pragma unroll
    for (int i = 0; i < 4; ++i)
        #pragma unroll
        for (int j = 0; j < 4; ++j) acc[i][j] = (f32x4){0.f, 0.f, 0.f, 0.f};

    for (int kc = 0; kc < C_DIM; kc += 64) {
        short8v a[2][4];                                  // A frags this chunk
        #pragma unroll
        for (int k2 = 0; k2 < 2; ++k2)
            #pragma unroll
            for (int nf = 0; nf < 4; ++nf)
                a[k2][nf] = *(const short8v*)(gA + (size_t)nf * 16 * C_DIM + kc + k2 * 32);

        __syncthreads();                                  // prev Bs reads done
        #pragma unroll
        for (int p = 0; p < 4; ++p)
            *(short8v*)&Bs[(nl + 32 * p) * 72 + kg * 8] = rb[p];
        __syncthreads();
        if (kc < C_DIM - 64) {                            // prefetch next B chunk
            #pragma unroll
            for (int p = 0; p < 4; ++p)
                rb[p] = *(const short8v*)&cbbf[(size_t)(j0 + nl + 32 * p) * C_DIM + kc + 64 + kg * 8];
        }

        #pragma unroll
        for (int kk = 0; kk < 2; ++kk) {
            short8v b[4];
            #pragma unroll
            for (int jf = 0; jf < 4; ++jf)
                b[jf] = *(const short8v*)&Bs[(wx * 64 + jf * 16 + c) * 72 + kk * 32 + g * 8];
            #pragma unroll
            for (int nf = 0; nf < 4; ++nf)
                #pragma unroll
                for (int jf = 0; jf < 4; ++jf)
                    acc[nf][jf] = __builtin_amdgcn_mfma_f32_16x16x32_bf16(
                        a[kk][nf], b[jf], acc[nf][jf], 0, 0, 0);
        }
    }

    // C layout: col(j) = lane&15, row(n) = (lane>>4)*4 + reg.  max over j.
    #pragma unroll
    for (int nf = 0; nf < 4; ++nf) {
        #pragma unroll
        for (int rr = 0; rr < 4; ++rr) {
            float mx = acc[nf][0][rr];
            #pragma unroll
            for (int jf = 1; jf < 4; ++jf) mx = fmaxf(mx, acc[nf][jf][rr]);
            #pragma unroll
            for (int off = 1; off < 16; off <<= 1)
                mx = fmaxf(mx, __shfl_xor(mx, off, 64));
            if (c == 0) smin[wy * 64 + nf * 16 + g * 4 + rr][wx] = -2.0f * mx;
        }
    }
    __syncthreads();
    if (tid < 128)
        tilemin[(size_t)bx * N_VEC + n0 + tid] = fminf(smin[tid][0], smin[tid][1]);
}

// ---------------------------------------------------------------------------
// Stage B1a: thr[n] = min_t tilemin[t][n] + MARGIN; also re-arms keys[n].
__global__ __launch_bounds__(256) void k_rowmin(const float* __restrict__ tilemin,
                                               float* __restrict__ thr,
                                               unsigned long long* __restrict__ keys) {
    __shared__ float red[4][64];
    const int nl = threadIdx.x & 63, tg = threadIdx.x >> 6;
    const int n = blockIdx.x * 64 + nl;
    float m = 3.4e38f;
    #pragma unroll
    for (int i = 0; i < 16; ++i)
        m = fminf(m, tilemin[(size_t)(tg * 16 + i) * N_VEC + n]);
    red[tg][nl] = m;
    __syncthreads();
    if (tg == 0) {
        thr[n] = fminf(fminf(red[0][nl], red[1][nl]),
                       fminf(red[2][nl], red[3][nl])) + MARGIN;
        keys[n] = ~0ull;
    }
}

// ---------------------------------------------------------------------------
// Stage B1b: build per-tile candidate lists (wave-aggregated compaction).
__global__ __launch_bounds__(256) void k_build(const float* __restrict__ tilemin,
                                               const float* __restrict__ thr,
                                               int* __restrict__ listlen,
                                               int* __restrict__ lists) {
    const int t = blockIdx.x;
    const int lane = threadIdx.x & 63;
    #pragma unroll
    for (int it = 0; it < 8; ++it) {
        int n = blockIdx.y * 2048 + it * 256 + threadIdx.x;
        bool qq = tilemin[(size_t)t * N_VEC + n] <= thr[n];
        unsigned long long mask = __ballot(qq);
        if (mask) {
            int ldr = __ffsll(mask) - 1;
            int base = 0;
            if (lane == ldr) base = atomicAdd(&listlen[t], __popcll(mask));
            base = __shfl(base, ldr, 64);
            if (qq) {
                int pre = __popcll(mask & ((1ull << lane) - 1ull));
                lists[t * N_VEC + base + pre] = n;
            }
        }
    }
}

// ---------------------------------------------------------------------------
// Stage B2: tile-centric exact refine (R7/R10 structure; z staged from zT with
// the R5-verbatim coalesced b128 pattern).  grid (64, 128).
__global__ __launch_bounds__(256) void k_refine2(const float* __restrict__ zT,
                                                 const float* __restrict__ cb,
                                                 const float* __restrict__ ce,
                                                 const float* __restrict__ A,
                                                 const int* __restrict__ listlen,
                                                 const int* __restrict__ lists,
                                                 unsigned long long* __restrict__ keys) {
    __shared__ float e_s[128 * 68];
    __shared__ float z_s[32 * 68];
    __shared__ int   rows_s[32];

    const int t = blockIdx.x;
    const int len = listlen[t];
    const int tid = threadIdx.x;
    const int jg = tid & 31, rg = tid >> 5;
    const int j0 = t * 128;

    for (int b0 = blockIdx.y * 32; b0 < len; b0 += 128 * 32) {
        const int nrows = min(32, len - b0);
        __syncthreads();                           // protect prev batch's LDS
        if (tid < 32)
            rows_s[tid] = lists[t * N_VEC + b0 + min(tid, nrows - 1)];  // pad dup row0

        float acc[4][4];
        #pragma unroll
        for (int rr = 0; rr < 4; ++rr)
            #pragma unroll
            for (int jj = 0; jj < 4; ++jj) acc[rr][jj] = 0.0f;

        for (int kc = 0; kc < C_DIM; kc += 64) {
            __syncthreads();
            {   // stage e chunk: 128 j x 64 k
                int jr = tid >> 1, ko = (tid & 1) * 32;
                #pragma unroll
                for (int i = 0; i < 8; ++i)
                    *(float4*)&e_s[jr * 68 + ko + i * 4] =
                        *(const float4*)&cb[(size_t)(j0 + jr) * C_DIM + kc + ko + i * 4];
            }
            {   // stage z chunk: 32 rows x 64 k from zT (R5-verbatim, coalesced)
                int r = tid >> 3, ko = (tid & 7) * 8;
                const float* zp = &zT[(size_t)rows_s[r] * C_DIM + kc + ko];
                *(float4*)&z_s[r * 68 + ko]     = *(const float4*)&zp[0];
                *(float4*)&z_s[r * 68 + ko + 4] = *(const float4*)&zp[4];
            }
            __syncthreads();

            #pragma unroll
            for (int k4 = 0; k4 < 16; ++k4) {
                float4 ef[4], zf[4];
                #pragma unroll
                for (int jj = 0; jj < 4; ++jj)
                    ef[jj] = *(const float4*)&e_s[(jg + 32 * jj) * 68 + k4 * 4];
                #pragma unroll
                for (int rr = 0; rr < 4; ++rr)
                    zf[rr] = *(const float4*)&z_s[(rg * 4 + rr) * 68 + k4 * 4];
                #pragma unroll
                for (int kk = 0; kk < 4; ++kk)       // k ascending: exact chain
                    #pragma unroll
                    for (int rr = 0; rr < 4; ++rr)
                        #pragma unroll
                        for (int jj = 0; jj < 4; ++jj)
                            acc[rr][jj] = fmaf(((const float*)&zf[rr])[kk],
                                               ((const float*)&ef[jj])[kk], acc[rr][jj]);
            }
        }

        // epilogue: exact d, packed key, min over jj then over jg lanes
        #pragma unroll
        for (int rr = 0; rr < 4; ++rr) {
            const int n = rows_s[rg * 4 + rr];
            const float An = A[n];
            unsigned long long best = ~0ull;
            #pragma unroll
            for (int jj = 0; jj < 4; ++jj) {
                int j = j0 + jg + 32 * jj;
                float tt = An + ce[j];
                float d = fmaf(-2.0f, acc[rr][jj], tt);   // == R2 epilogue bits
                unsigned int sd = __float_as_uint(d);
                sd = (sd & 0x80000000u) ? ~sd : (sd | 0x80000000u);
                unsigned long long key = ((unsigned long long)sd << 32) | (unsigned)j;
                best = key < best ? key : best;
            }
            #pragma unroll
            for (int off = 16; off > 0; off >>= 1) {      // reduce 32 jg lanes
                unsigned long long o = __shfl_xor(best, off, 64);
                best = o < best ? o : best;
            }
            if (jg == 0) atomicMin(&keys[n], best);
        }
    }
}

// ---------------------------------------------------------------------------
// gather z_q + idx unpack + histogram + fp64 SSE reduction
__global__ __launch_bounds__(256) void k_gather(const float* __restrict__ z,
                                                const float* __restrict__ cb,
                                                const unsigned long long* __restrict__ keys,
                                                float* __restrict__ out,
                                                float* __restrict__ out_idx,
                                                int* __restrict__ counts,
                                                double* __restrict__ sse) {
    int bh = blockIdx.x;                 // b*32 + h
    int b = bh >> 5, h = bh & 31;
    int tid = threadIdx.x;
    __shared__ int sidx[32];
    if (tid < 32) {
        int n = b * 1024 + h * 32 + tid;
        unsigned long long k = keys[n];
        int idx = (int)(k & 0xFFFFFFFFull);
        sidx[tid] = idx;
        out_idx[n] = (float)idx;
        atomicAdd(&counts[idx], 1);
    }
    __syncthreads();
    int w = tid & 31, cy = tid >> 5;
    int jid = sidx[w];
    const float* cbr = cb + (size_t)jid * C_DIM;
    size_t zb = (size_t)b * 262144 + h * 32 + w;

    double acc = 0.0;
    #pragma unroll 4
    for (int cc = 0; cc < 32; ++cc) {
        int c = cc * 8 + cy;
        float e = cbr[c];
        size_t zi = zb + (size_t)c * 1024;
        float d = e - z[zi];
        out[zi] = e;
        acc += (double)(d * d);
    }
    #pragma unroll
    for (int off = 32; off > 0; off >>= 1) acc += __shfl_down(acc, off, 64);
    __shared__ double sh[4];
    if ((tid & 63) == 0) sh[tid >> 6] = acc;
    __syncthreads();
    if (tid == 0) atomicAdd(sse, sh[0] + sh[1] + sh[2] + sh[3]);
}

// ---------------------------------------------------------------------------
// Gram matrix M = Wn^T Wn  (256x256), j-split with float atomics
__global__ __launch_bounds__(256) void k_gram(const float* __restrict__ cb,
                                              const float* __restrict__ rn,
                                              float* __restrict__ M) {
    __shared__ float aT[64][68];
    __shared__ float bT[64][68];
    int k0 = blockIdx.x * 64, l0 = blockIdx.y * 64;
    int jc0 = blockIdx.z * 256;
    int tid = threadIdx.x;
    int tk = tid & 15, tl = tid >> 4;
    float acc[4][4];
    #pragma unroll
    for (int i = 0; i < 4; ++i)
        #pragma unroll
        for (int l = 0; l < 4; ++l) acc[i][l] = 0.0f;

    for (int jc = jc0; jc < jc0 + 256; jc += 64) {
        __syncthreads();
        {
            int kk = tid & 63, jj0 = tid >> 6;
            #pragma unroll
            for (int p = 0; p < 16; ++p) {
                int jj = p * 4 + jj0;
                float r = rn[jc + jj];
                const float* row = cb + (size_t)(jc + jj) * C_DIM;
                aT[jj][kk] = row[k0 + kk] * r;
                bT[jj][kk] = row[l0 + kk] * r;
            }
        }
        __syncthreads();
        #pragma unroll 8
        for (int jj = 0; jj < 64; ++jj) {
            float4 av = *(const float4*)&aT[jj][tk * 4];
            float4 bv = *(const float4*)&bT[jj][tl * 4];
            float a4[4] = {av.x, av.y, av.z, av.w};
            float b4[4] = {bv.x, bv.y, bv.z, bv.w};
            #pragma unroll
            for (int i = 0; i < 4; ++i)
                #pragma unroll
                for (int l = 0; l < 4; ++l)
                    acc[i][l] = fmaf(a4[i], b4[l], acc[i][l]);
        }
    }
    #pragma unroll
    for (int i = 0; i < 4; ++i)
        #pragma unroll
        for (int l = 0; l < 4; ++l)
            atomicAdd(&M[(size_t)(k0 + tk * 4 + i) * C_DIM + l0 + tl * 4 + l], acc[i][l]);
}

// ---------------------------------------------------------------------------
// finalize scalars: loss, ortho = (||M||_F^2 - n_e)/n_e^2, perplexity
__global__ __launch_bounds__(256) void k_final(const float* __restrict__ M,
                                               const int* __restrict__ counts,
                                               const double* __restrict__ accum,
                                               float* __restrict__ out_scalars) {
    int tid = threadIdx.x;
    __shared__ double sh[4];

    double s = 0.0;
    for (int i = tid; i < C_DIM * C_DIM; i += 256) {
        double m = M[i];
        s += m * m;
    }
    #pragma unroll
    for (int off = 32; off > 0; off >>= 1) s += __shfl_down(s, off, 64);
    if ((tid & 63) == 0) sh[tid >> 6] = s;
    __syncthreads();
    double S = sh[0] + sh[1] + sh[2] + sh[3];
    __syncthreads();

    double H = 0.0;
    for (int j = tid; j < N_E; j += 256) {
        double p = counts[j] * (1.0 / (double)N_VEC);
        H += p * log(p + 1e-10);
    }
    #pragma unroll
    for (int off = 32; off > 0; off >>= 1) H += __shfl_down(H, off, 64);
    if ((tid & 63) == 0) sh[tid >> 6] = H;
    __syncthreads();

    if (tid == 0) {
        double Hs = sh[0] + sh[1] + sh[2] + sh[3];
        out_scalars[0] = (float)(1.25 * accum[0] / (double)N_ELEM);        // loss
        out_scalars[1] = (float)((S - (double)N_E) / ((double)N_E * N_E)); // ortho
        out_scalars[2] = (float)exp(-Hs);                                  // perplexity
    }
}

// ---------------------------------------------------------------------------
extern "C" void kernel_launch(void* const* d_in, const int* in_sizes, int n_in,
                              void* d_out, int out_size, void* d_ws, size_t ws_size,
                              hipStream_t stream) {
    (void)in_sizes; (void)n_in; (void)out_size; (void)ws_size;
    const float* z  = (const float*)d_in[0];
    const float* cb = (const float*)d_in[1];
    float* out = (float*)d_out;

    char* ws = (char*)d_ws;
    int* counts            = (int*)(ws + WS_COUNTS);
    float* M               = (float*)(ws + WS_M);
    double* accum          = (double*)(ws + WS_ACCUM);
    int* listlen           = (int*)(ws + WS_LISTLEN);
    float* ce              = (float*)(ws + WS_CE);
    float* rn              = (float*)(ws + WS_RN);
    float* A               = (float*)(ws + WS_A);
    unsigned long long* keys = (unsigned long long*)(ws + WS_KEYS);
    int* lists             = (int*)(ws + WS_LISTS);
    float* tilemin         = (float*)(ws + WS_TILEMIN);
    unsigned short* zbf    = (unsigned short*)(ws + WS_ZBF);
    unsigned short* cbbf   = (unsigned short*)(ws + WS_CBBF);
    float* thr             = (float*)(ws + WS_THR);
    float* zT              = (float*)(ws + WS_ZT);

    float* out_scalars = out + N_ELEM;       // loss, ortho, perplexity
    float* out_idx     = out + N_ELEM + 3;   // 16384 idx as float

    hipMemsetAsync(ws, 0, WS_ZERO_BYTES, stream);   // counts + M + accum + listlen

    k_cbprep<<<N_E, 256, 0, stream>>>(cb, ce, rn, cbbf);
    k_ztrans<<<N_VEC / 64, 256, 0, stream>>>(z, zbf, zT, A);
    k_mfma<<<8192, 256, 0, stream>>>(zbf, cbbf, tilemin);
    k_rowmin<<<N_VEC / 64, 256, 0, stream>>>(tilemin, thr, keys);
    k_build<<<dim3(64, 8), 256, 0, stream>>>(tilemin, thr, listlen, lists);
    k_refine2<<<dim3(64, 128), 256, 0, stream>>>(zT, cb, ce, A, listlen, lists, keys);
    k_gather<<<512, 256, 0, stream>>>(z, cb, keys, out, out_idx, counts, accum);
    k_gram<<<dim3(4, 4, 32), 256, 0, stream>>>(cb, rn, M);
    k_final<<<1, 256, 0, stream>>>(M, counts, accum, out_scalars);
}

// Round 12
// 424.287 us; speedup vs baseline: 1.1030x; 1.1030x over previous
//
#include <hip/hip_runtime.h>
#include <hip/hip_bf16.h>
#include <math.h>

// ---------------------------------------------------------------------------
// VQ quantizer:
//   in[0] = z        (16,256,32,32) fp32   -> N=16384 vectors of C=256
//   in[1] = codebook (8192,256)     fp32
//   out   = [ z_q (B,C,H,W) 4194304 | loss | ortho | perplexity | idx(16384) as float ]
//
// idx strategy (two-stage, bit-matching the R2..R11 passing semantics):
//   Stage A: bf16 MFMA GEMM; tilemin[t][n] = -2*max_j dot_approx (err<=1.54e-4)
//   Stage B: rows whose tilemin is within MARGIN of rowmin get the EXACT fp32
//            chain recomputed tile-centrically; d = fmaf(-2,acc, A_n + ce_j)
//            == R2 bits; packed-key atomicMin, lowest-index tie-break.
//
// R12 = R11 with k_mfma staging switched to global_load_lds (width=16, DMA
// direct to LDS, linear [128][64] layout) + XOR slot-swizzle applied to BOTH
// the global source and the LDS read (rule: both-sides-or-neither).  MFMA
// kc/kk/acc order is verbatim R7/R10 -> tilemin bits unchanged.
// ---------------------------------------------------------------------------

#define N_E     8192
#define C_DIM   256
#define N_VEC   16384            // 16*32*32
#define N_ELEM  4194304          // 16*256*32*32
#define MARGIN  6.0e-4f

// ws layout (bytes) -- zero-init fields packed first (single memset)
#define WS_COUNTS   0            // int[8192]                 32768
#define WS_M        32768        // float[65536]              262144
#define WS_ACCUM    294912       // double[2]                 16
#define WS_LISTLEN  294928       // int[64]                   256
#define WS_ZERO_BYTES 295184
#define WS_CE       295184       // float[8192]               32768
#define WS_RN       327952       // float[8192]               32768
#define WS_A        360720       // float[16384]              65536
#define WS_KEYS     426256       // u64[16384]                131072
#define WS_LISTS    557328       // int[64*16384]             4194304
#define WS_TILEMIN  4751632      // float[64*16384] [t][n]    4194304
#define WS_ZBF      8945936      // ushort[16384*256]         8388608
#define WS_CBBF     17334544     // ushort[8192*256]          4194304
#define WS_THR      21528848     // float[16384]              65536
#define WS_ZT       21594384     // float[16384*256]          16777216

typedef short short8v __attribute__((ext_vector_type(8)));
typedef float f32x4  __attribute__((ext_vector_type(4)));

__device__ inline unsigned short f2bf(float f) {       // RNE fp32->bf16 (no NaN in data)
    unsigned int x = __float_as_uint(f);
    return (unsigned short)((x + 0x7fffu + ((x >> 16) & 1u)) >> 16);
}

// async 16B/lane global->LDS DMA (gfx950).  LDS dest = wave-uniform base +
// lane*16; global src is per-lane.
__device__ inline void gload16(const void* g, void* l) {
    __builtin_amdgcn_global_load_lds(
        (const __attribute__((address_space(1))) unsigned int*)g,
        (__attribute__((address_space(3))) unsigned int*)l, 16, 0, 0);
}

// ---------------------------------------------------------------------------
// codebook prep: row sqnorm ce (bits == R2..R11), recip norm rn, bf16 cast
__global__ __launch_bounds__(256) void k_cbprep(const float* __restrict__ cb,
                                                float* __restrict__ ce,
                                                float* __restrict__ rn,
                                                unsigned short* __restrict__ cbbf) {
    int j = blockIdx.x;
    int tid = threadIdx.x;
    float v = cb[(size_t)j * C_DIM + tid];
    cbbf[(size_t)j * C_DIM + tid] = f2bf(v);
    float s = v * v;
    #pragma unroll
    for (int off = 32; off > 0; off >>= 1) s += __shfl_down(s, off, 64);
    __shared__ float sh[4];
    if ((tid & 63) == 0) sh[tid >> 6] = s;
    __syncthreads();
    if (tid == 0) {
        float t = sh[0] + sh[1] + sh[2] + sh[3];
        ce[j] = t;
        rn[j] = 1.0f / sqrtf(t);
    }
}

// ---------------------------------------------------------------------------
// z prep: LDS-staged transpose -> zbf (bf16) + zT (fp32), both with coalesced
// 16B/lane writes; A[n] computed from the LDS tile with the R2-VERBATIM
// k-ascending fmaf chain (same values, same order -> identical bits).
__global__ __launch_bounds__(256) void k_ztrans(const float* __restrict__ z,
                                                unsigned short* __restrict__ zbf,
                                                float* __restrict__ zT,
                                                float* __restrict__ A) {
    __shared__ float tile[64 * 260];             // [hw][c], stride 260
    const int tid = threadIdx.x;
    const int n0 = blockIdx.x * 64;
    const int b = n0 >> 10, hw0 = n0 & 1023;
    const float* zp = z + (size_t)b * 262144 + hw0;

    const int hw = tid & 63, cg = tid >> 6;      // 4 c per pass, coalesced over hw
    #pragma unroll 8
    for (int p = 0; p < 64; ++p) {
        int c = p * 4 + cg;
        tile[hw * 260 + c] = zp[(size_t)c * 1024 + hw];
    }
    __syncthreads();

    if (tid < 64) {                              // A[n]: R2-verbatim chain
        float a = 0.0f;
        #pragma unroll 8
        for (int c = 0; c < C_DIM; ++c) {
            float v = tile[tid * 260 + c];
            a = fmaf(v, v, a);
        }
        A[n0 + tid] = a;
    }

    const int r = tid >> 2, q = tid & 3;         // row, 64-c quarter
    unsigned short* dst = zbf + (size_t)(n0 + r) * C_DIM + q * 64;
    float* dstT         = zT  + (size_t)(n0 + r) * C_DIM + q * 64;
    const float* src = &tile[r * 260 + q * 64];
    #pragma unroll
    for (int i = 0; i < 8; ++i) {
        f32x4 lo = *(const f32x4*)&src[i * 8];
        f32x4 hi = *(const f32x4*)&src[i * 8 + 4];
        *(f32x4*)&dstT[i * 8]     = lo;
        *(f32x4*)&dstT[i * 8 + 4] = hi;
        short8v u;
        #pragma unroll
        for (int x = 0; x < 4; ++x) { u[x] = (short)f2bf(lo[x]); u[4 + x] = (short)f2bf(hi[x]); }
        *(short8v*)(dst + i * 8) = u;            // 16B/lane, rows contiguous
    }
}

// ---------------------------------------------------------------------------
// Stage A: bf16 MFMA GEMM, 128n x 128j per block (4 waves, 2x2), K=256,
// 2-level XCD swizzle (R7-verbatim mapping).  Staging via global_load_lds
// DMA into LINEAR [128][64]-short tiles; bank conflicts handled by XOR slot
// swizzle on BOTH the global source and the LDS read:
//   LDS(row, s) = G(row, s ^ (row&7));  read G(row,slot) at s = slot^(row&7).
// Quarter-wave bank audit: 8 slot-groups x 2 rows = two clean 128B sweeps.
// MFMA kc/kk/acc order verbatim R7 -> tilemin bits unchanged.
__global__ __launch_bounds__(256) void k_mfma(const unsigned short* __restrict__ zbf,
                                              const unsigned short* __restrict__ cbbf,
                                              float* __restrict__ tilemin) {
    __shared__ unsigned short As[128 * 64];   // [n][k] linear (DMA dest)
    __shared__ unsigned short Bs[128 * 64];   // [j][k] linear
    __shared__ float smin[128][2];

    const int tid = threadIdx.x;
    const int lin = blockIdx.x;
    const int x = lin & 7, r = lin >> 3;                  // XCD, rank within
    const int jp = r >> 7, q = r & 127;
    const int by = x * 16 + (q >> 3), bx = jp * 8 + (q & 7);
    const int n0 = by * 128, j0 = bx * 128;
    const int wave = tid >> 6, lane = tid & 63;
    const int wx = wave & 1, wy = wave >> 1;              // wave tile: 64n x 64j
    const int g = lane >> 4, c = lane & 15;

    // DMA staging: wave covers rows [wave*32, wave*32+32) of both tiles.
    // Each inst writes 1KB = 8 rows; lane l -> row +(l>>3), LDS slot (l&7),
    // fetching pre-swizzled global slot (l&7)^(l>>3).
    const int lrow  = lane >> 3;
    const int lslot = (lane & 7) ^ lrow;
    const int rbase = wave * 32;                          // wave-uniform

    f32x4 acc[4][4];
    #pragma unroll
    for (int i = 0; i < 4; ++i)
        #pragma unroll
        for (int j = 0; j < 4; ++j) acc[i][j] = (f32x4){0.f, 0.f, 0.f, 0.f};

    for (int kc = 0; kc < C_DIM; kc += 64) {
        __syncthreads();                                  // prev reads done
        #pragma unroll
        for (int i = 0; i < 4; ++i) {
            const int row8 = rbase + i * 8;
            const unsigned short* ga =
                zbf  + (size_t)(n0 + row8 + lrow) * C_DIM + kc + lslot * 8;
            const unsigned short* gb =
                cbbf + (size_t)(j0 + row8 + lrow) * C_DIM + kc + lslot * 8;
            gload16(ga, &As[row8 * 64]);
            gload16(gb, &Bs[row8 * 64]);
        }
        __syncthreads();                                  // vmcnt(0): tiles resident

        #pragma unroll
        for (int kk = 0; kk < 2; ++kk) {
            short8v a[4], b[4];
            #pragma unroll
            for (int f = 0; f < 4; ++f) {
                const int row = wy * 64 + f * 16 + c;
                a[f] = *(const short8v*)&As[row * 64 + (((kk * 4 + g) ^ (c & 7)) * 8)];
            }
            #pragma unroll
            for (int f = 0; f < 4; ++f) {
                const int row = wx * 64 + f * 16 + c;
                b[f] = *(const short8v*)&Bs[row * 64 + (((kk * 4 + g) ^ (c & 7)) * 8)];
            }
            #pragma unroll
            for (int nf = 0; nf < 4; ++nf)
                #pragma unroll
                for (int jf = 0; jf < 4; ++jf)
                    acc[nf][jf] = __builtin_amdgcn_mfma_f32_16x16x32_bf16(
                        a[nf], b[jf], acc[nf][jf], 0, 0, 0);
        }
    }

    // C layout: col(j) = lane&15, row(n) = (lane>>4)*4 + reg.  max over j.
    #pragma unroll
    for (int nf = 0; nf < 4; ++nf) {
        #pragma unroll
        for (int rr = 0; rr < 4; ++rr) {
            float mx = acc[nf][0][rr];
            #pragma unroll
            for (int jf = 1; jf < 4; ++jf) mx = fmaxf(mx, acc[nf][jf][rr]);
            #pragma unroll
            for (int off = 1; off < 16; off <<= 1)
                mx = fmaxf(mx, __shfl_xor(mx, off, 64));
            if (c == 0) smin[wy * 64 + nf * 16 + g * 4 + rr][wx] = -2.0f * mx;
        }
    }
    __syncthreads();
    if (tid < 128)
        tilemin[(size_t)bx * N_VEC + n0 + tid] = fminf(smin[tid][0], smin[tid][1]);
}

// ---------------------------------------------------------------------------
// Stage B1a: thr[n] = min_t tilemin[t][n] + MARGIN; also re-arms keys[n].
__global__ __launch_bounds__(256) void k_rowmin(const float* __restrict__ tilemin,
                                               float* __restrict__ thr,
                                               unsigned long long* __restrict__ keys) {
    __shared__ float red[4][64];
    const int nl = threadIdx.x & 63, tg = threadIdx.x >> 6;
    const int n = blockIdx.x * 64 + nl;
    float m = 3.4e38f;
    #pragma unroll
    for (int i = 0; i < 16; ++i)
        m = fminf(m, tilemin[(size_t)(tg * 16 + i) * N_VEC + n]);
    red[tg][nl] = m;
    __syncthreads();
    if (tg == 0) {
        thr[n] = fminf(fminf(red[0][nl], red[1][nl]),
                       fminf(red[2][nl], red[3][nl])) + MARGIN;
        keys[n] = ~0ull;
    }
}

// ---------------------------------------------------------------------------
// Stage B1b: build per-tile candidate lists (wave-aggregated compaction).
__global__ __launch_bounds__(256) void k_build(const float* __restrict__ tilemin,
                                               const float* __restrict__ thr,
                                               int* __restrict__ listlen,
                                               int* __restrict__ lists) {
    const int t = blockIdx.x;
    const int lane = threadIdx.x & 63;
    #pragma unroll
    for (int it = 0; it < 8; ++it) {
        int n = blockIdx.y * 2048 + it * 256 + threadIdx.x;
        bool qq = tilemin[(size_t)t * N_VEC + n] <= thr[n];
        unsigned long long mask = __ballot(qq);
        if (mask) {
            int ldr = __ffsll(mask) - 1;
            int base = 0;
            if (lane == ldr) base = atomicAdd(&listlen[t], __popcll(mask));
            base = __shfl(base, ldr, 64);
            if (qq) {
                int pre = __popcll(mask & ((1ull << lane) - 1ull));
                lists[t * N_VEC + base + pre] = n;
            }
        }
    }
}

// ---------------------------------------------------------------------------
// Stage B2: tile-centric exact refine (R7/R10 structure; z staged from zT with
// the R5-verbatim coalesced b128 pattern).  grid (64, 128).
__global__ __launch_bounds__(256) void k_refine2(const float* __restrict__ zT,
                                                 const float* __restrict__ cb,
                                                 const float* __restrict__ ce,
                                                 const float* __restrict__ A,
                                                 const int* __restrict__ listlen,
                                                 const int* __restrict__ lists,
                                                 unsigned long long* __restrict__ keys) {
    __shared__ float e_s[128 * 68];
    __shared__ float z_s[32 * 68];
    __shared__ int   rows_s[32];

    const int t = blockIdx.x;
    const int len = listlen[t];
    const int tid = threadIdx.x;
    const int jg = tid & 31, rg = tid >> 5;
    const int j0 = t * 128;

    for (int b0 = blockIdx.y * 32; b0 < len; b0 += 128 * 32) {
        const int nrows = min(32, len - b0);
        __syncthreads();                           // protect prev batch's LDS
        if (tid < 32)
            rows_s[tid] = lists[t * N_VEC + b0 + min(tid, nrows - 1)];  // pad dup row0

        float acc[4][4];
        #pragma unroll
        for (int rr = 0; rr < 4; ++rr)
            #pragma unroll
            for (int jj = 0; jj < 4; ++jj) acc[rr][jj] = 0.0f;

        for (int kc = 0; kc < C_DIM; kc += 64) {
            __syncthreads();
            {   // stage e chunk: 128 j x 64 k
                int jr = tid >> 1, ko = (tid & 1) * 32;
                #pragma unroll
                for (int i = 0; i < 8; ++i)
                    *(float4*)&e_s[jr * 68 + ko + i * 4] =
                        *(const float4*)&cb[(size_t)(j0 + jr) * C_DIM + kc + ko + i * 4];
            }
            {   // stage z chunk: 32 rows x 64 k from zT (R5-verbatim, coalesced)
                int r = tid >> 3, ko = (tid & 7) * 8;
                const float* zp = &zT[(size_t)rows_s[r] * C_DIM + kc + ko];
                *(float4*)&z_s[r * 68 + ko]     = *(const float4*)&zp[0];
                *(float4*)&z_s[r * 68 + ko + 4] = *(const float4*)&zp[4];
            }
            __syncthreads();

            #pragma unroll
            for (int k4 = 0; k4 < 16; ++k4) {
                float4 ef[4], zf[4];
                #pragma unroll
                for (int jj = 0; jj < 4; ++jj)
                    ef[jj] = *(const float4*)&e_s[(jg + 32 * jj) * 68 + k4 * 4];
                #pragma unroll
                for (int rr = 0; rr < 4; ++rr)
                    zf[rr] = *(const float4*)&z_s[(rg * 4 + rr) * 68 + k4 * 4];
                #pragma unroll
                for (int kk = 0; kk < 4; ++kk)       // k ascending: exact chain
                    #pragma unroll
                    for (int rr = 0; rr < 4; ++rr)
                        #pragma unroll
                        for (int jj = 0; jj < 4; ++jj)
                            acc[rr][jj] = fmaf(((const float*)&zf[rr])[kk],
                                               ((const float*)&ef[jj])[kk], acc[rr][jj]);
            }
        }

        // epilogue: exact d, packed key, min over jj then over jg lanes
        #pragma unroll
        for (int rr = 0; rr < 4; ++rr) {
            const int n = rows_s[rg * 4 + rr];
            const float An = A[n];
            unsigned long long best = ~0ull;
            #pragma unroll
            for (int jj = 0; jj < 4; ++jj) {
                int j = j0 + jg + 32 * jj;
                float tt = An + ce[j];
                float d = fmaf(-2.0f, acc[rr][jj], tt);   // == R2 epilogue bits
                unsigned int sd = __float_as_uint(d);
                sd = (sd & 0x80000000u) ? ~sd : (sd | 0x80000000u);
                unsigned long long key = ((unsigned long long)sd << 32) | (unsigned)j;
                best = key < best ? key : best;
            }
            #pragma unroll
            for (int off = 16; off > 0; off >>= 1) {      // reduce 32 jg lanes
                unsigned long long o = __shfl_xor(best, off, 64);
                best = o < best ? o : best;
            }
            if (jg == 0) atomicMin(&keys[n], best);
        }
    }
}

// ---------------------------------------------------------------------------
// gather z_q + idx unpack + histogram + fp64 SSE reduction
__global__ __launch_bounds__(256) void k_gather(const float* __restrict__ z,
                                                const float* __restrict__ cb,
                                                const unsigned long long* __restrict__ keys,
                                                float* __restrict__ out,
                                                float* __restrict__ out_idx,
                                                int* __restrict__ counts,
                                                double* __restrict__ sse) {
    int bh = blockIdx.x;                 // b*32 + h
    int b = bh >> 5, h = bh & 31;
    int tid = threadIdx.x;
    __shared__ int sidx[32];
    if (tid < 32) {
        int n = b * 1024 + h * 32 + tid;
        unsigned long long k = keys[n];
        int idx = (int)(k & 0xFFFFFFFFull);
        sidx[tid] = idx;
        out_idx[n] = (float)idx;
        atomicAdd(&counts[idx], 1);
    }
    __syncthreads();
    int w = tid & 31, cy = tid >> 5;
    int jid = sidx[w];
    const float* cbr = cb + (size_t)jid * C_DIM;
    size_t zb = (size_t)b * 262144 + h * 32 + w;

    double acc = 0.0;
    #pragma unroll 4
    for (int cc = 0; cc < 32; ++cc) {
        int c = cc * 8 + cy;
        float e = cbr[c];
        size_t zi = zb + (size_t)c * 1024;
        float d = e - z[zi];
        out[zi] = e;
        acc += (double)(d * d);
    }
    #pragma unroll
    for (int off = 32; off > 0; off >>= 1) acc += __shfl_down(acc, off, 64);
    __shared__ double sh[4];
    if ((tid & 63) == 0) sh[tid >> 6] = acc;
    __syncthreads();
    if (tid == 0) atomicAdd(sse, sh[0] + sh[1] + sh[2] + sh[3]);
}

// ---------------------------------------------------------------------------
// Gram matrix M = Wn^T Wn  (256x256), j-split with float atomics
__global__ __launch_bounds__(256) void k_gram(const float* __restrict__ cb,
                                              const float* __restrict__ rn,
                                              float* __restrict__ M) {
    __shared__ float aT[64][68];
    __shared__ float bT[64][68];
    int k0 = blockIdx.x * 64, l0 = blockIdx.y * 64;
    int jc0 = blockIdx.z * 256;
    int tid = threadIdx.x;
    int tk = tid & 15, tl = tid >> 4;
    float acc[4][4];
    #pragma unroll
    for (int i = 0; i < 4; ++i)
        #pragma unroll
        for (int l = 0; l < 4; ++l) acc[i][l] = 0.0f;

    for (int jc = jc0; jc < jc0 + 256; jc += 64) {
        __syncthreads();
        {
            int kk = tid & 63, jj0 = tid >> 6;
            #pragma unroll
            for (int p = 0; p < 16; ++p) {
                int jj = p * 4 + jj0;
                float r = rn[jc + jj];
                const float* row = cb + (size_t)(jc + jj) * C_DIM;
                aT[jj][kk] = row[k0 + kk] * r;
                bT[jj][kk] = row[l0 + kk] * r;
            }
        }
        __syncthreads();
        #pragma unroll 8
        for (int jj = 0; jj < 64; ++jj) {
            float4 av = *(const float4*)&aT[jj][tk * 4];
            float4 bv = *(const float4*)&bT[jj][tl * 4];
            float a4[4] = {av.x, av.y, av.z, av.w};
            float b4[4] = {bv.x, bv.y, bv.z, bv.w};
            #pragma unroll
            for (int i = 0; i < 4; ++i)
                #pragma unroll
                for (int l = 0; l < 4; ++l)
                    acc[i][l] = fmaf(a4[i], b4[l], acc[i][l]);
        }
    }
    #pragma unroll
    for (int i = 0; i < 4; ++i)
        #pragma unroll
        for (int l = 0; l < 4; ++l)
            atomicAdd(&M[(size_t)(k0 + tk * 4 + i) * C_DIM + l0 + tl * 4 + l], acc[i][l]);
}

// ---------------------------------------------------------------------------
// finalize scalars: loss, ortho = (||M||_F^2 - n_e)/n_e^2, perplexity
__global__ __launch_bounds__(256) void k_final(const float* __restrict__ M,
                                               const int* __restrict__ counts,
                                               const double* __restrict__ accum,
                                               float* __restrict__ out_scalars) {
    int tid = threadIdx.x;
    __shared__ double sh[4];

    double s = 0.0;
    for (int i = tid; i < C_DIM * C_DIM; i += 256) {
        double m = M[i];
        s += m * m;
    }
    #pragma unroll
    for (int off = 32; off > 0; off >>= 1) s += __shfl_down(s, off, 64);
    if ((tid & 63) == 0) sh[tid >> 6] = s;
    __syncthreads();
    double S = sh[0] + sh[1] + sh[2] + sh[3];
    __syncthreads();

    double H = 0.0;
    for (int j = tid; j < N_E; j += 256) {
        double p = counts[j] * (1.0 / (double)N_VEC);
        H += p * log(p + 1e-10);
    }
    #pragma unroll
    for (int off = 32; off > 0; off >>= 1) H += __shfl_down(H, off, 64);
    if ((tid & 63) == 0) sh[tid >> 6] = H;
    __syncthreads();

    if (tid == 0) {
        double Hs = sh[0] + sh[1] + sh[2] + sh[3];
        out_scalars[0] = (float)(1.25 * accum[0] / (double)N_ELEM);        // loss
        out_scalars[1] = (float)((S - (double)N_E) / ((double)N_E * N_E)); // ortho
        out_scalars[2] = (float)exp(-Hs);                                  // perplexity
    }
}

// ---------------------------------------------------------------------------
extern "C" void kernel_launch(void* const* d_in, const int* in_sizes, int n_in,
                              void* d_out, int out_size, void* d_ws, size_t ws_size,
                              hipStream_t stream) {
    (void)in_sizes; (void)n_in; (void)out_size; (void)ws_size;
    const float* z  = (const float*)d_in[0];
    const float* cb = (const float*)d_in[1];
    float* out = (float*)d_out;

    char* ws = (char*)d_ws;
    int* counts            = (int*)(ws + WS_COUNTS);
    float* M               = (float*)(ws + WS_M);
    double* accum          = (double*)(ws + WS_ACCUM);
    int* listlen           = (int*)(ws + WS_LISTLEN);
    float* ce              = (float*)(ws + WS_CE);
    float* rn              = (float*)(ws + WS_RN);
    float* A               = (float*)(ws + WS_A);
    unsigned long long* keys = (unsigned long long*)(ws + WS_KEYS);
    int* lists             = (int*)(ws + WS_LISTS);
    float* tilemin         = (float*)(ws + WS_TILEMIN);
    unsigned short* zbf    = (unsigned short*)(ws + WS_ZBF);
    unsigned short* cbbf   = (unsigned short*)(ws + WS_CBBF);
    float* thr             = (float*)(ws + WS_THR);
    float* zT              = (float*)(ws + WS_ZT);

    float* out_scalars = out + N_ELEM;       // loss, ortho, perplexity
    float* out_idx     = out + N_ELEM + 3;   // 16384 idx as float

    hipMemsetAsync(ws, 0, WS_ZERO_BYTES, stream);   // counts + M + accum + listlen

    k_cbprep<<<N_E, 256, 0, stream>>>(cb, ce, rn, cbbf);
    k_ztrans<<<N_VEC / 64, 256, 0, stream>>>(z, zbf, zT, A);
    k_mfma<<<8192, 256, 0, stream>>>(zbf, cbbf, tilemin);
    k_rowmin<<<N_VEC / 64, 256, 0, stream>>>(tilemin, thr, keys);
    k_build<<<dim3(64, 8), 256, 0, stream>>>(tilemin, thr, listlen, lists);
    k_refine2<<<dim3(64, 128), 256, 0, stream>>>(zT, cb, ce, A, listlen, lists, keys);
    k_gather<<<512, 256, 0, stream>>>(z, cb, keys, out, out_idx, counts, accum);
    k_gram<<<dim3(4, 4, 32), 256, 0, stream>>>(cb, rn, M);
    k_final<<<1, 256, 0, stream>>>(M, counts, accum, out_scalars);
}